// Round 7
// baseline (113.362 us; speedup 1.0000x reference)
//
#include <hip/hip_runtime.h>
#include <math.h>

#define A0_INV (1.0f/0.529177249f)

typedef __bf16 bf16x8 __attribute__((ext_vector_type(8)));
typedef __bf16 bf16x4 __attribute__((ext_vector_type(4)));
typedef float  f32x4  __attribute__((ext_vector_type(4)));

__device__ __constant__ float c_SIGMA[8] = {
    0.5515909f, 1.8886297f, 1.3225029f, 1.2316629f,
    2.1884933f, 1.7750372f, 1.3677907f, 1.3820058f};

__device__ __forceinline__ float celu01(float x) {
    return x > 0.0f ? x : 0.1f * (__expf(x * 10.0f) - 1.0f);
}
__device__ __forceinline__ float softplusf_(float x) {
    return fmaxf(x, 0.0f) + log1pf(__expf(-fabsf(x)));
}
__device__ __forceinline__ __bf16 u16_to_bf16(unsigned short u) {
    __bf16 b; __builtin_memcpy(&b, &u, 2); return b;
}
__device__ __forceinline__ unsigned short f_to_bf16_bits(float f) {
    __bf16 b = (__bf16)f; unsigned short u; __builtin_memcpy(&u, &b, 2); return u;
}

// ---- pack weights (K,OUT) f32 -> B-fragment order bf16: Bp[e][nt][kt][lane][8]
__device__ __forceinline__ void pack_one(int idx, const float* __restrict__ W,
                                         __bf16* __restrict__ Bp,
                                         int K, int OUT, int NT, int KT)
{
    int lane = idx & 63;
    int rest = idx >> 6;
    int kt = rest % KT; rest /= KT;
    int nt = rest % NT;
    int e  = rest / NT;
    int col = nt * 16 + (lane & 15);
    int k0  = kt * 32 + (lane >> 4) * 8;
    bf16x8 o;
#pragma unroll
    for (int j = 0; j < 8; ++j) {
        int k = k0 + j;
        float v = (k < K) ? W[((long)e * K + k) * OUT + col] : 0.0f;
        o[j] = (__bf16)v;
    }
    *((bf16x8*)Bp + idx) = o;
}

__global__ __launch_bounds__(256) void pack_all_kernel(
    const float* __restrict__ cW1, const float* __restrict__ cW2, const float* __restrict__ cW3,
    const float* __restrict__ W1,  const float* __restrict__ W2,  const float* __restrict__ W3,
    __bf16* bp_c1, __bf16* bp_c2, __bf16* bp_c3,
    __bf16* bp_e1, __bf16* bp_e2, __bf16* bp_e3)
{
    int idx = blockIdx.x * 256 + threadIdx.x;
    if      (idx <   7680) pack_one(idx,          cW1, bp_c1, 384, 160, 10, 12);
    else if (idx <  10240) pack_one(idx - 7680,   cW2, bp_c2, 160, 128,  8,  5);
    else if (idx <  11776) pack_one(idx - 10240,  cW3, bp_c3, 128,  96,  6,  4);
    else if (idx <  78336) pack_one(idx - 11776,  W1,  bp_e1, 386, 160, 10, 13);
    else if (idx <  98816) pack_one(idx - 78336,  W2,  bp_e2, 160, 128,  8,  5);
    else if (idx < 111104) pack_one(idx - 98816,  W3,  bp_e3, 128,  96,  6,  4);
}

// ---- one MFMA MLP layer over a 64-atom LDS tile, 8 waves (2 Mw x 4 Nw) ----
template<int NT, int KT, int INS, int OUTS, bool CELU>
__device__ __forceinline__ void mlp_layer8(const __bf16* sIn, const bf16x8* __restrict__ Bp,
                                           const float* __restrict__ bias, __bf16* sOut, int tid)
{
    const int lane = tid & 63;
    const int wid  = tid >> 6;       // 0..7
    const int mw   = wid >> 2;       // 0..1
    const int nw   = wid & 3;        // 0..3
    const int r16  = lane & 15;
    const int g    = lane >> 4;
    constexpr int NJ = (NT + 3) / 4;
    f32x4 acc[2][NJ];
#pragma unroll
    for (int mi = 0; mi < 2; ++mi)
#pragma unroll
        for (int j = 0; j < NJ; ++j)
            acc[mi][j] = (f32x4){0.f, 0.f, 0.f, 0.f};

    bf16x8 bcur[NJ], bnxt[NJ];
#pragma unroll
    for (int j = 0; j < NJ; ++j) {
        const int nt = nw + 4 * j;
        if (nt < NT) bcur[j] = Bp[(nt * KT) * 64 + lane];
    }
    for (int kt = 0; kt < KT; ++kt) {
        bf16x8 a[2];
#pragma unroll
        for (int mi = 0; mi < 2; ++mi)
            a[mi] = *(const bf16x8*)(sIn + ((mw * 2 + mi) * 16 + r16) * INS + kt * 32 + g * 8);
        if (kt + 1 < KT) {
#pragma unroll
            for (int j = 0; j < NJ; ++j) {
                const int nt = nw + 4 * j;
                if (nt < NT) bnxt[j] = Bp[(nt * KT + kt + 1) * 64 + lane];
            }
        }
#pragma unroll
        for (int j = 0; j < NJ; ++j) {
            const int nt = nw + 4 * j;
            if (nt < NT) {
#pragma unroll
                for (int mi = 0; mi < 2; ++mi)
                    acc[mi][j] = __builtin_amdgcn_mfma_f32_16x16x32_bf16(a[mi], bcur[j], acc[mi][j], 0, 0, 0);
            }
        }
#pragma unroll
        for (int j = 0; j < NJ; ++j) bcur[j] = bnxt[j];
    }
#pragma unroll
    for (int j = 0; j < NJ; ++j) {
        const int nt = nw + 4 * j;
        if (nt < NT) {
            const float bb = bias[nt * 16 + r16];
#pragma unroll
            for (int mi = 0; mi < 2; ++mi)
#pragma unroll
                for (int r = 0; r < 4; ++r) {
                    float v = acc[mi][j][r] + bb;
                    if (CELU) v = celu01(v);
                    sOut[((mw * 2 + mi) * 16 + g * 4 + r) * OUTS + nt * 16 + r16] = (__bf16)v;
                }
        }
    }
}

// vectorized final-layer dot: h[96] (bf16, 16B-aligned) . w4[96] (f32)
__device__ __forceinline__ float l4_dot(const __bf16* __restrict__ h,
                                        const float* __restrict__ w4)
{
    float acc = 0.f;
#pragma unroll
    for (int u8 = 0; u8 < 12; ++u8) {
        bf16x8 hv = *(const bf16x8*)(h + u8 * 8);
        float4 wa = *(const float4*)(w4 + u8 * 8);
        float4 wb = *(const float4*)(w4 + u8 * 8 + 4);
        acc = fmaf((float)hv[0], wa.x, acc);
        acc = fmaf((float)hv[1], wa.y, acc);
        acc = fmaf((float)hv[2], wa.z, acc);
        acc = fmaf((float)hv[3], wa.w, acc);
        acc = fmaf((float)hv[4], wb.x, acc);
        acc = fmaf((float)hv[5], wb.y, acc);
        acc = fmaf((float)hv[6], wb.z, acc);
        acc = fmaf((float)hv[7], wb.w, acc);
    }
    return acc;
}

// ------------- fused chi MLP + per-molecule q/ESP/coulomb (1 block = 1 mol) -
__global__ __launch_bounds__(512) void chimol_kernel(
    const float* __restrict__ aev, const int* __restrict__ species,
    const float* __restrict__ coords, const float* __restrict__ netq,
    const __bf16* __restrict__ bp1, const __bf16* __restrict__ bp2, const __bf16* __restrict__ bp3,
    const float* __restrict__ b1, const float* __restrict__ b2, const float* __restrict__ b3,
    const float* __restrict__ W4, const float* __restrict__ b4,
    __bf16* __restrict__ aev16,
    int* __restrict__ blockCounts, int* __restrict__ rank,
    float* __restrict__ qv, float* __restrict__ esp, float* __restrict__ coul,
    float* __restrict__ o_species, float* __restrict__ o_q)
{
    __shared__ __align__(16) unsigned char smem[50176 + 21504];   // 70 KB
    __shared__ float sChi[64];
    __shared__ float sx[64], sy[64], sz[64], sq[64], ss2[64];
    __shared__ float sEsp[8][64];
    __bf16* sFeat = (__bf16*)smem;              // [64][392] (384 used)
    __bf16* sAct1 = (__bf16*)(smem + 50176);    // [64][168] (160 used)
    __bf16* sAct2 = (__bf16*)smem;              // [64][136] (alias dead sFeat)
    __bf16* sAct3 = (__bf16*)(smem + 17408);    // [64][104]
    const int t = threadIdx.x;
    const int m = blockIdx.x;
    const long base = (long)m * 64;

    if (aev16) {
        for (int i = t; i < 64 * 96; i += 512) {
            int row = i / 96, c4 = (i - row * 96) * 4;
            float4 v = *(const float4*)(aev + (base + row) * 384 + c4);
            bf16x4 o = {(__bf16)v.x, (__bf16)v.y, (__bf16)v.z, (__bf16)v.w};
            *(bf16x4*)(sFeat + row * 392 + c4) = o;
            *(bf16x4*)(aev16 + (base + row) * 384 + c4) = o;
        }
    } else {
        for (int i = t; i < 64 * 96; i += 512) {
            int row = i / 96, c4 = (i - row * 96) * 4;
            float4 v = *(const float4*)(aev + (base + row) * 384 + c4);
            bf16x4 o = {(__bf16)v.x, (__bf16)v.y, (__bf16)v.z, (__bf16)v.w};
            *(bf16x4*)(sFeat + row * 392 + c4) = o;
        }
    }
    __syncthreads();
    mlp_layer8<10, 12, 392, 168, true>(sFeat, (const bf16x8*)bp1, b1, sAct1, t);
    __syncthreads();
    mlp_layer8<8, 5, 168, 136, true>(sAct1, (const bf16x8*)bp2, b2, sAct2, t);
    __syncthreads();
    mlp_layer8<6, 4, 136, 104, true>(sAct2, (const bf16x8*)bp3, b3, sAct3, t);
    __syncthreads();
    if (t < 64) {
        float acc = l4_dot(sAct3 + t * 104, W4);
        float chiv = softplusf_(acc + b4[0]);
        long atom = base + t;
        int s = species[atom];
        if (s == -1) chiv = 0.f;
        sChi[t] = chiv;
        // species histogram + in-block rank (wave 0, ballot-based)
        unsigned long long mym = 0;
#pragma unroll
        for (int e = 0; e < 8; ++e) {
            unsigned long long bm = __ballot(s == e);
            if (t == e) blockCounts[m * 8 + e] = (int)__popcll(bm);
            if (s == e) mym = bm;
        }
        if (s >= 0) rank[atom] = (int)__popcll(mym & ((1ull << t) - 1ull));
    }
    __syncthreads();

    // ---- mol part: 8 groups of 8 pair-iterations ----
    const int j = t & 63, grp = t >> 6;
    const int atom = (int)base + j;
    int s = species[atom];
    float pad = (s != -1) ? 1.0f : 0.0f;
    float chij = sChi[j];

    float cs = chij, na = pad;   // identical reduction in every wave
#pragma unroll
    for (int o = 32; o > 0; o >>= 1) {
        cs += __shfl_xor(cs, o);
        na += __shfl_xor(na, o);
    }
    float qc = netq[m];
    float k_net = 1.0f + fabsf(qc) / cs;
    float chi_mean = cs / na;
    float k_p = (qc > 0.0f) ? k_net : 1.0f;
    float k_n = (qc < 0.0f) ? k_net : 1.0f;
    float qj = (-k_n * chij + k_p * chi_mean) * pad;

    float sg = c_SIGMA[s < 0 ? 0 : s];
    float x = coords[atom * 3 + 0], y = coords[atom * 3 + 1], z = coords[atom * 3 + 2];
    if (grp == 0) { sx[j] = x; sy[j] = y; sz[j] = z; sq[j] = qj; ss2[j] = sg * sg; }
    __syncthreads();

    float s2j = sg * sg;
    float ej = 0.0f;
#pragma unroll
    for (int k = 0; k < 8; ++k) {
        int i = grp * 8 + k;
        if (i == j) continue;
        float dx = sx[i] - x, dy = sy[i] - y, dz = sz[i] - z;
        float d = sqrtf(dx * dx + dy * dy + dz * dz + 1e-16f) * A0_INV;
        float ssum = fmaxf(ss2[i] + s2j, 1e-8f);
        float jij = erff(d * rsqrtf(2.0f * ssum)) / d;
        ej = fmaf(sq[i], jij, ej);
    }
    sEsp[grp][j] = ej;
    __syncthreads();
    if (grp == 0) {
        float e = ((sEsp[0][j] + sEsp[1][j]) + (sEsp[2][j] + sEsp[3][j]))
                + ((sEsp[4][j] + sEsp[5][j]) + (sEsp[6][j] + sEsp[7][j]));
        e *= pad;
        float ce = qj * e;
#pragma unroll
        for (int o = 32; o > 0; o >>= 1) ce += __shfl_xor(ce, o);
        if (j == 0) coul[m] = 0.5f * ce;
        qv[atom] = qj;
        esp[atom] = e;
        o_species[atom] = (float)s;
        o_q[atom] = qj;
    }
}

// ---------------- scan (two-level) + work-list build -----------------------
__global__ void bucket_scan_kernel(int* __restrict__ blockCounts,
                                   int* __restrict__ counts, int* __restrict__ offs,
                                   int* __restrict__ workItems, int* __restrict__ workCount,
                                   int nb)
{
    __shared__ int segSum[8][8];
    __shared__ int tot[8];
    const int tid = threadIdx.x;   // 64 threads
    const int seg = tid >> 3, e = tid & 7;
    const int per = (nb + 7) / 8;
    const int b0 = seg * per, b1 = min(b0 + per, nb);
    int run = 0;
    for (int b = b0; b < b1; ++b) run += blockCounts[b * 8 + e];
    segSum[seg][e] = run;
    __syncthreads();
    if (tid < 8) {
        int r = 0;
        for (int s2 = 0; s2 < 8; ++s2) { int c = segSum[s2][tid]; segSum[s2][tid] = r; r += c; }
        tot[tid] = r;
    }
    __syncthreads();
    int runp = segSum[seg][e];
    for (int b = b0; b < b1; ++b) {
        int c = blockCounts[b * 8 + e];
        blockCounts[b * 8 + e] = runp;
        runp += c;
    }
    if (tid == 0) {
        int o = 0;
        for (int i = 0; i < 8; ++i) { offs[i] = o; counts[i] = tot[i]; o += tot[i]; }
        offs[8] = o;
    }
    if (tid < 8) {
        int pos = 0;
        for (int i = 0; i < tid; ++i) pos += (tot[i] + 63) >> 6;
        int nt_e = (tot[tid] + 63) >> 6;
        for (int k = 0; k < nt_e; ++k) workItems[pos + k] = (tid << 20) | (k * 64);
        if (tid == 7) workCount[0] = pos + nt_e;
    }
}

// ---------------- fill: scatter atom ids + zero-init outat -----------------
__global__ __launch_bounds__(256) void bucket_fill_kernel(
    const int* __restrict__ species, const int* __restrict__ blockCounts,
    const int* __restrict__ offs, const int* __restrict__ rank,
    int* __restrict__ bidx, float* __restrict__ outat, int A)
{
    int a = blockIdx.x * 256 + threadIdx.x;
    if (a < A) {
        outat[a] = 0.0f;
        int s = species[a];
        if (s >= 0)
            bidx[offs[s] + blockCounts[(a >> 6) * 8 + s] + rank[a]] = a;
    }
}

// ---- A-fragment loads straight from global (bf16 or fp32 fallback) --------
__device__ __forceinline__ bf16x8 loadA16(const __bf16* __restrict__ aev16,
                                          int atom, int kt, int g)
{
    bf16x8 z = {};
    if (atom < 0) return z;
    return *(const bf16x8*)(aev16 + (long)atom * 384 + kt * 32 + g * 8);
}
__device__ __forceinline__ bf16x8 loadAf(const float* __restrict__ aev,
                                         int atom, int kt, int g)
{
    bf16x8 z = {};
    if (atom < 0) return z;
    const float* p = aev + (long)atom * 384 + kt * 32 + g * 8;
    float4 va = *(const float4*)p, vb = *(const float4*)(p + 4);
    bf16x8 r = {(__bf16)va.x, (__bf16)va.y, (__bf16)va.z, (__bf16)va.w,
                (__bf16)vb.x, (__bf16)vb.y, (__bf16)vb.z, (__bf16)vb.w};
    return r;
}

// ---------------- routed expert MLP: no staging, A-frags from global -------
template<bool HAVE16>
__global__ __launch_bounds__(512, 6) void expert_mfma_kernel(
    const float* __restrict__ aev, const __bf16* __restrict__ aev16,
    const float* __restrict__ qv, const float* __restrict__ esp,
    const __bf16* __restrict__ bp1, const __bf16* __restrict__ bp2, const __bf16* __restrict__ bp3,
    const float* __restrict__ b1, const float* __restrict__ b2, const float* __restrict__ b3,
    const float* __restrict__ W4, const float* __restrict__ b4,
    const int* __restrict__ counts, const int* __restrict__ offs, const int* __restrict__ bidx,
    const int* __restrict__ workItems, const int* __restrict__ workCount,
    float* __restrict__ outat)
{
    const int bid = blockIdx.x;
    if (bid >= workCount[0]) return;
    const int wi = workItems[bid];
    const int e = wi >> 20;
    const int start = wi & 0xFFFFF;
    const int cnt = counts[e];

    __shared__ __align__(16) unsigned char smem[21504 + 17408];  // 38.9 KB
    __shared__ int said[64];
    __shared__ unsigned int sQE[64];
    __bf16* sAct1 = (__bf16*)smem;              // [64][168]
    __bf16* sAct2 = (__bf16*)(smem + 21504);    // [64][136]
    __bf16* sAct3 = (__bf16*)smem;              // [64][104] (alias dead sAct1)
    const int t = threadIdx.x;

    if (t < 64) {
        int a_ = (start + t < cnt) ? bidx[offs[e] + start + t] : -1;
        said[t] = a_;
        float q = 0.f, es = 0.f;
        if (a_ >= 0) { q = qv[a_]; es = esp[a_]; }
        sQE[t] = ((unsigned)f_to_bf16_bits(es) << 16) | f_to_bf16_bits(q);
    }
    __syncthreads();

    // ---- Layer 1: NT=10, KT=13 (kt 12 = q/esp columns), A from global ----
    {
        const int lane = t & 63, wid = t >> 6;
        const int mw = wid >> 2, nw = wid & 3;
        const int r16 = lane & 15, g = lane >> 4;
        const int atom0 = said[(mw * 2 + 0) * 16 + r16];
        const int atom1 = said[(mw * 2 + 1) * 16 + r16];
        const bf16x8* Bp = (const bf16x8*)bp1 + (size_t)e * 10 * 13 * 64;
        constexpr int NJ = 3;
        f32x4 acc[2][NJ];
#pragma unroll
        for (int mi = 0; mi < 2; ++mi)
#pragma unroll
            for (int j = 0; j < NJ; ++j) acc[mi][j] = (f32x4){0.f, 0.f, 0.f, 0.f};

        bf16x8 bcur[NJ], bnxt[NJ];
#pragma unroll
        for (int j = 0; j < NJ; ++j) {
            const int nt = nw + 4 * j;
            if (nt < 10) bcur[j] = Bp[(nt * 13) * 64 + lane];
        }
        bf16x8 a0c = HAVE16 ? loadA16(aev16, atom0, 0, g) : loadAf(aev, atom0, 0, g);
        bf16x8 a1c = HAVE16 ? loadA16(aev16, atom1, 0, g) : loadAf(aev, atom1, 0, g);

        for (int kt = 0; kt < 12; ++kt) {
#pragma unroll
            for (int j = 0; j < NJ; ++j) {
                const int nt = nw + 4 * j;
                if (nt < 10) bnxt[j] = Bp[(nt * 13 + kt + 1) * 64 + lane];
            }
            bf16x8 a0n, a1n;
            if (kt < 11) {
                a0n = HAVE16 ? loadA16(aev16, atom0, kt + 1, g) : loadAf(aev, atom0, kt + 1, g);
                a1n = HAVE16 ? loadA16(aev16, atom1, kt + 1, g) : loadAf(aev, atom1, kt + 1, g);
            }
#pragma unroll
            for (int j = 0; j < NJ; ++j) {
                const int nt = nw + 4 * j;
                if (nt < 10) {
                    acc[0][j] = __builtin_amdgcn_mfma_f32_16x16x32_bf16(a0c, bcur[j], acc[0][j], 0, 0, 0);
                    acc[1][j] = __builtin_amdgcn_mfma_f32_16x16x32_bf16(a1c, bcur[j], acc[1][j], 0, 0, 0);
                }
            }
#pragma unroll
            for (int j = 0; j < NJ; ++j) bcur[j] = bnxt[j];
            if (kt < 11) { a0c = a0n; a1c = a1n; }
        }
        // kt = 12: only k=384 (q), 385 (esp) nonzero -> g==0, j=0,1
        bf16x8 aq0 = {}, aq1 = {};
        if (g == 0) {
            unsigned qe0 = sQE[(mw * 2 + 0) * 16 + r16];
            unsigned qe1 = sQE[(mw * 2 + 1) * 16 + r16];
            aq0[0] = u16_to_bf16((unsigned short)(qe0 & 0xffff));
            aq0[1] = u16_to_bf16((unsigned short)(qe0 >> 16));
            aq1[0] = u16_to_bf16((unsigned short)(qe1 & 0xffff));
            aq1[1] = u16_to_bf16((unsigned short)(qe1 >> 16));
        }
#pragma unroll
        for (int j = 0; j < NJ; ++j) {
            const int nt = nw + 4 * j;
            if (nt < 10) {
                acc[0][j] = __builtin_amdgcn_mfma_f32_16x16x32_bf16(aq0, bcur[j], acc[0][j], 0, 0, 0);
                acc[1][j] = __builtin_amdgcn_mfma_f32_16x16x32_bf16(aq1, bcur[j], acc[1][j], 0, 0, 0);
            }
        }
        // epilogue -> sAct1
#pragma unroll
        for (int j = 0; j < NJ; ++j) {
            const int nt = nw + 4 * j;
            if (nt < 10) {
                const float bb = b1[e * 160 + nt * 16 + r16];
#pragma unroll
                for (int mi = 0; mi < 2; ++mi)
#pragma unroll
                    for (int r = 0; r < 4; ++r) {
                        float v = acc[mi][j][r] + bb;
                        v = celu01(v);
                        sAct1[((mw * 2 + mi) * 16 + g * 4 + r) * 168 + nt * 16 + r16] = (__bf16)v;
                    }
            }
        }
    }
    __syncthreads();
    mlp_layer8<8, 5, 168, 136, true>(sAct1, (const bf16x8*)bp2 + (size_t)e * 8 * 5 * 64,
                                     b2 + e * 128, sAct2, t);
    __syncthreads();
    mlp_layer8<6, 4, 136, 104, true>(sAct2, (const bf16x8*)bp3 + (size_t)e * 6 * 4 * 64,
                                     b3 + e * 96, sAct3, t);
    __syncthreads();
    if (t < 64) {
        int atom = said[t];
        if (atom >= 0) {
            float acc = l4_dot(sAct3 + t * 104, W4 + e * 96);
            outat[atom] = acc + b4[e];
        }
    }
}

// ---------------- per-molecule energy -----------------------------
__global__ __launch_bounds__(64) void energy_kernel(
    const float* __restrict__ outat, const float* __restrict__ coul,
    float* __restrict__ o_energy)
{
    int m = blockIdx.x, t = threadIdx.x;
    float v = outat[m * 64 + t];
#pragma unroll
    for (int o = 32; o > 0; o >>= 1) v += __shfl_xor(v, o);
    if (t == 0) o_energy[m] = v + coul[m];
}

extern "C" void kernel_launch(void* const* d_in, const int* in_sizes, int n_in,
                              void* d_out, int out_size, void* d_ws, size_t ws_size,
                              hipStream_t stream)
{
    const int*   species = (const int*)  d_in[0];
    const float* coords  = (const float*)d_in[1];
    const float* netq    = (const float*)d_in[2];
    const float* aev     = (const float*)d_in[3];
    const float* cW1 = (const float*)d_in[4];
    const float* cb1 = (const float*)d_in[5];
    const float* cW2 = (const float*)d_in[6];
    const float* cb2 = (const float*)d_in[7];
    const float* cW3 = (const float*)d_in[8];
    const float* cb3 = (const float*)d_in[9];
    const float* cW4 = (const float*)d_in[10];
    const float* cb4 = (const float*)d_in[11];
    const float* W1  = (const float*)d_in[12];
    const float* b1  = (const float*)d_in[13];
    const float* W2  = (const float*)d_in[14];
    const float* b2  = (const float*)d_in[15];
    const float* W3  = (const float*)d_in[16];
    const float* b3  = (const float*)d_in[17];
    const float* W4  = (const float*)d_in[18];
    const float* b4  = (const float*)d_in[19];

    const int N = in_sizes[2];          // 512
    const int n = in_sizes[0] / N;      // 64
    const int A = N * n;                // 32768
    const int nb64 = A / 64;            // 512
    const int maxWork = nb64 + 8;       // 520

    // ---- workspace layout ----
    float* fbase   = (float*)d_ws;
    float* qv      = fbase;
    float* esp     = fbase + (size_t)A;
    float* outat   = fbase + (size_t)2 * A;
    float* coul    = fbase + (size_t)3 * A;
    int*   counts  = (int*)(coul + N);
    int*   offs    = counts + 8;
    int*   workCount = offs + 9;
    int*   workItems = workCount + 1;            // maxWork ints
    int*   blockCounts = workItems + maxWork;    // nb64*8 ints
    int*   rank    = blockCounts + nb64 * 8;     // A ints
    int*   bidx    = rank + A;                   // A ints
    uintptr_t p = ((uintptr_t)(bidx + A) + 15) & ~(uintptr_t)15;
    __bf16* bp_c1 = (__bf16*)p; p += (size_t)10 * 12 * 512 * 2;
    __bf16* bp_c2 = (__bf16*)p; p += (size_t)8  * 5  * 512 * 2;
    __bf16* bp_c3 = (__bf16*)p; p += (size_t)6  * 4  * 512 * 2;
    __bf16* bp_e1 = (__bf16*)p; p += (size_t)8 * 10 * 13 * 512 * 2;
    __bf16* bp_e2 = (__bf16*)p; p += (size_t)8 * 8  * 5  * 512 * 2;
    __bf16* bp_e3 = (__bf16*)p; p += (size_t)8 * 6  * 4  * 512 * 2;
    p = (p + 15) & ~(uintptr_t)15;
    __bf16* aev16 = (__bf16*)p;
    size_t need = (p - (uintptr_t)d_ws) + (size_t)A * 384 * 2;
    if (ws_size < need) aev16 = nullptr;         // fp32 fallback path

    float* o_species = (float*)d_out;        // A elems (species as float)
    float* o_energy  = o_species + A;        // N elems
    float* o_q       = o_energy + N;         // A elems

    pack_all_kernel<<<(111104 + 255) / 256, 256, 0, stream>>>(
        cW1, cW2, cW3, W1, W2, W3, bp_c1, bp_c2, bp_c3, bp_e1, bp_e2, bp_e3);

    chimol_kernel<<<nb64, 512, 0, stream>>>(aev, species, coords, netq,
                                            bp_c1, bp_c2, bp_c3,
                                            cb1, cb2, cb3, cW4, cb4,
                                            aev16, blockCounts, rank,
                                            qv, esp, coul, o_species, o_q);
    bucket_scan_kernel<<<1, 64, 0, stream>>>(blockCounts, counts, offs,
                                             workItems, workCount, nb64);
    bucket_fill_kernel<<<(A + 255) / 256, 256, 0, stream>>>(species, blockCounts, offs,
                                                            rank, bidx, outat, A);
    if (aev16)
        expert_mfma_kernel<true><<<maxWork, 512, 0, stream>>>(
            aev, aev16, qv, esp, bp_e1, bp_e2, bp_e3, b1, b2, b3, W4, b4,
            counts, offs, bidx, workItems, workCount, outat);
    else
        expert_mfma_kernel<false><<<maxWork, 512, 0, stream>>>(
            aev, aev16, qv, esp, bp_e1, bp_e2, bp_e3, b1, b2, b3, W4, b4,
            counts, offs, bidx, workItems, workCount, outat);
    energy_kernel<<<N, 64, 0, stream>>>(outat, coul, o_energy);
}

// Round 8
// 94.942 us; speedup vs baseline: 1.1940x; 1.1940x over previous
//
#include <hip/hip_runtime.h>
#include <math.h>

#define A0_INV (1.0f/0.529177249f)

typedef __bf16 bf16x8 __attribute__((ext_vector_type(8)));
typedef __bf16 bf16x4 __attribute__((ext_vector_type(4)));
typedef float  f32x4  __attribute__((ext_vector_type(4)));

__device__ __constant__ float c_SIGMA[8] = {
    0.5515909f, 1.8886297f, 1.3225029f, 1.2316629f,
    2.1884933f, 1.7750372f, 1.3677907f, 1.3820058f};

__device__ __forceinline__ float celu01(float x) {
    return x > 0.0f ? x : 0.1f * (__expf(x * 10.0f) - 1.0f);
}
__device__ __forceinline__ float softplusf_(float x) {
    return fmaxf(x, 0.0f) + log1pf(__expf(-fabsf(x)));
}
__device__ __forceinline__ __bf16 u16_to_bf16(unsigned short u) {
    __bf16 b; __builtin_memcpy(&b, &u, 2); return b;
}
__device__ __forceinline__ unsigned short f_to_bf16_bits(float f) {
    __bf16 b = (__bf16)f; unsigned short u; __builtin_memcpy(&u, &b, 2); return u;
}

// ---- pack weights (K,OUT) f32 -> B-fragment order bf16: Bp[e][nt][kt][lane][8]
__device__ __forceinline__ void pack_one(int idx, const float* __restrict__ W,
                                         __bf16* __restrict__ Bp,
                                         int K, int OUT, int NT, int KT)
{
    int lane = idx & 63;
    int rest = idx >> 6;
    int kt = rest % KT; rest /= KT;
    int nt = rest % NT;
    int e  = rest / NT;
    int col = nt * 16 + (lane & 15);
    int k0  = kt * 32 + (lane >> 4) * 8;
    bf16x8 o;
#pragma unroll
    for (int j = 0; j < 8; ++j) {
        int k = k0 + j;
        float v = (k < K) ? W[((long)e * K + k) * OUT + col] : 0.0f;
        o[j] = (__bf16)v;
    }
    *((bf16x8*)Bp + idx) = o;
}

__global__ __launch_bounds__(256) void pack_all_kernel(
    const float* __restrict__ cW1, const float* __restrict__ cW2, const float* __restrict__ cW3,
    const float* __restrict__ W1,  const float* __restrict__ W2,  const float* __restrict__ W3,
    __bf16* bp_c1, __bf16* bp_c2, __bf16* bp_c3,
    __bf16* bp_e1, __bf16* bp_e2, __bf16* bp_e3)
{
    int idx = blockIdx.x * 256 + threadIdx.x;
    if      (idx <   7680) pack_one(idx,          cW1, bp_c1, 384, 160, 10, 12);
    else if (idx <  10240) pack_one(idx - 7680,   cW2, bp_c2, 160, 128,  8,  5);
    else if (idx <  11776) pack_one(idx - 10240,  cW3, bp_c3, 128,  96,  6,  4);
    else if (idx <  78336) pack_one(idx - 11776,  W1,  bp_e1, 386, 160, 10, 13);
    else if (idx <  98816) pack_one(idx - 78336,  W2,  bp_e2, 160, 128,  8,  5);
    else if (idx < 111104) pack_one(idx - 98816,  W3,  bp_e3, 128,  96,  6,  4);
}

// ---- one MFMA MLP layer over a 64-atom LDS tile, 8 waves (2 Mw x 4 Nw) ----
template<int NT, int KT, int INS, int OUTS, bool CELU>
__device__ __forceinline__ void mlp_layer8(const __bf16* sIn, const bf16x8* __restrict__ Bp,
                                           const float* __restrict__ bias, __bf16* sOut, int tid)
{
    const int lane = tid & 63;
    const int wid  = tid >> 6;       // 0..7
    const int mw   = wid >> 2;       // 0..1
    const int nw   = wid & 3;        // 0..3
    const int r16  = lane & 15;
    const int g    = lane >> 4;
    constexpr int NJ = (NT + 3) / 4;
    f32x4 acc[2][NJ];
#pragma unroll
    for (int mi = 0; mi < 2; ++mi)
#pragma unroll
        for (int j = 0; j < NJ; ++j)
            acc[mi][j] = (f32x4){0.f, 0.f, 0.f, 0.f};

    bf16x8 bcur[NJ], bnxt[NJ];
#pragma unroll
    for (int j = 0; j < NJ; ++j) {
        const int nt = nw + 4 * j;
        if (nt < NT) bcur[j] = Bp[(nt * KT) * 64 + lane];
    }
    for (int kt = 0; kt < KT; ++kt) {
        bf16x8 a[2];
#pragma unroll
        for (int mi = 0; mi < 2; ++mi)
            a[mi] = *(const bf16x8*)(sIn + ((mw * 2 + mi) * 16 + r16) * INS + kt * 32 + g * 8);
        if (kt + 1 < KT) {
#pragma unroll
            for (int j = 0; j < NJ; ++j) {
                const int nt = nw + 4 * j;
                if (nt < NT) bnxt[j] = Bp[(nt * KT + kt + 1) * 64 + lane];
            }
        }
#pragma unroll
        for (int j = 0; j < NJ; ++j) {
            const int nt = nw + 4 * j;
            if (nt < NT) {
#pragma unroll
                for (int mi = 0; mi < 2; ++mi)
                    acc[mi][j] = __builtin_amdgcn_mfma_f32_16x16x32_bf16(a[mi], bcur[j], acc[mi][j], 0, 0, 0);
            }
        }
#pragma unroll
        for (int j = 0; j < NJ; ++j) bcur[j] = bnxt[j];
    }
#pragma unroll
    for (int j = 0; j < NJ; ++j) {
        const int nt = nw + 4 * j;
        if (nt < NT) {
            const float bb = bias[nt * 16 + r16];
#pragma unroll
            for (int mi = 0; mi < 2; ++mi)
#pragma unroll
                for (int r = 0; r < 4; ++r) {
                    float v = acc[mi][j][r] + bb;
                    if (CELU) v = celu01(v);
                    sOut[((mw * 2 + mi) * 16 + g * 4 + r) * OUTS + nt * 16 + r16] = (__bf16)v;
                }
        }
    }
}

// vectorized final-layer dot: h[96] (bf16, 16B-aligned) . w4[96] (f32)
__device__ __forceinline__ float l4_dot(const __bf16* __restrict__ h,
                                        const float* __restrict__ w4)
{
    float acc = 0.f;
#pragma unroll
    for (int u8 = 0; u8 < 12; ++u8) {
        bf16x8 hv = *(const bf16x8*)(h + u8 * 8);
        float4 wa = *(const float4*)(w4 + u8 * 8);
        float4 wb = *(const float4*)(w4 + u8 * 8 + 4);
        acc = fmaf((float)hv[0], wa.x, acc);
        acc = fmaf((float)hv[1], wa.y, acc);
        acc = fmaf((float)hv[2], wa.z, acc);
        acc = fmaf((float)hv[3], wa.w, acc);
        acc = fmaf((float)hv[4], wb.x, acc);
        acc = fmaf((float)hv[5], wb.y, acc);
        acc = fmaf((float)hv[6], wb.z, acc);
        acc = fmaf((float)hv[7], wb.w, acc);
    }
    return acc;
}

// ------------- fused chi MLP + per-molecule q/ESP/coulomb (1 block = 1 mol) -
__global__ __launch_bounds__(512) void chimol_kernel(
    const float* __restrict__ aev, const int* __restrict__ species,
    const float* __restrict__ coords, const float* __restrict__ netq,
    const __bf16* __restrict__ bp1, const __bf16* __restrict__ bp2, const __bf16* __restrict__ bp3,
    const float* __restrict__ b1, const float* __restrict__ b2, const float* __restrict__ b3,
    const float* __restrict__ W4, const float* __restrict__ b4,
    __bf16* __restrict__ aev16,
    int* __restrict__ blockCounts, int* __restrict__ rank,
    float* __restrict__ qv, float* __restrict__ esp, float* __restrict__ coul,
    float* __restrict__ o_species, float* __restrict__ o_q)
{
    __shared__ __align__(16) unsigned char smem[50176 + 21504];   // 70 KB
    __shared__ float sChi[64];
    __shared__ float sx[64], sy[64], sz[64], sq[64], ss2[64];
    __shared__ float sEsp[8][64];
    __bf16* sFeat = (__bf16*)smem;              // [64][392] (384 used)
    __bf16* sAct1 = (__bf16*)(smem + 50176);    // [64][168] (160 used)
    __bf16* sAct2 = (__bf16*)smem;              // [64][136] (alias dead sFeat)
    __bf16* sAct3 = (__bf16*)(smem + 17408);    // [64][104]
    const int t = threadIdx.x;
    const int m = blockIdx.x;
    const long base = (long)m * 64;

    if (aev16) {
        for (int i = t; i < 64 * 96; i += 512) {
            int row = i / 96, c4 = (i - row * 96) * 4;
            float4 v = *(const float4*)(aev + (base + row) * 384 + c4);
            bf16x4 o = {(__bf16)v.x, (__bf16)v.y, (__bf16)v.z, (__bf16)v.w};
            *(bf16x4*)(sFeat + row * 392 + c4) = o;
            *(bf16x4*)(aev16 + (base + row) * 384 + c4) = o;
        }
    } else {
        for (int i = t; i < 64 * 96; i += 512) {
            int row = i / 96, c4 = (i - row * 96) * 4;
            float4 v = *(const float4*)(aev + (base + row) * 384 + c4);
            bf16x4 o = {(__bf16)v.x, (__bf16)v.y, (__bf16)v.z, (__bf16)v.w};
            *(bf16x4*)(sFeat + row * 392 + c4) = o;
        }
    }
    __syncthreads();
    mlp_layer8<10, 12, 392, 168, true>(sFeat, (const bf16x8*)bp1, b1, sAct1, t);
    __syncthreads();
    mlp_layer8<8, 5, 168, 136, true>(sAct1, (const bf16x8*)bp2, b2, sAct2, t);
    __syncthreads();
    mlp_layer8<6, 4, 136, 104, true>(sAct2, (const bf16x8*)bp3, b3, sAct3, t);
    __syncthreads();
    if (t < 64) {
        float acc = l4_dot(sAct3 + t * 104, W4);
        float chiv = softplusf_(acc + b4[0]);
        long atom = base + t;
        int s = species[atom];
        if (s == -1) chiv = 0.f;
        sChi[t] = chiv;
        // species histogram + in-block rank (wave 0, ballot-based)
        unsigned long long mym = 0;
#pragma unroll
        for (int e = 0; e < 8; ++e) {
            unsigned long long bm = __ballot(s == e);
            if (t == e) blockCounts[m * 8 + e] = (int)__popcll(bm);
            if (s == e) mym = bm;
        }
        if (s >= 0) rank[atom] = (int)__popcll(mym & ((1ull << t) - 1ull));
    }
    __syncthreads();

    // ---- mol part: 8 groups of 8 pair-iterations ----
    const int j = t & 63, grp = t >> 6;
    const int atom = (int)base + j;
    int s = species[atom];
    float pad = (s != -1) ? 1.0f : 0.0f;
    float chij = sChi[j];

    float cs = chij, na = pad;   // identical reduction in every wave
#pragma unroll
    for (int o = 32; o > 0; o >>= 1) {
        cs += __shfl_xor(cs, o);
        na += __shfl_xor(na, o);
    }
    float qc = netq[m];
    float k_net = 1.0f + fabsf(qc) / cs;
    float chi_mean = cs / na;
    float k_p = (qc > 0.0f) ? k_net : 1.0f;
    float k_n = (qc < 0.0f) ? k_net : 1.0f;
    float qj = (-k_n * chij + k_p * chi_mean) * pad;

    float sg = c_SIGMA[s < 0 ? 0 : s];
    float x = coords[atom * 3 + 0], y = coords[atom * 3 + 1], z = coords[atom * 3 + 2];
    if (grp == 0) { sx[j] = x; sy[j] = y; sz[j] = z; sq[j] = qj; ss2[j] = sg * sg; }
    __syncthreads();

    float s2j = sg * sg;
    float ej = 0.0f;
#pragma unroll
    for (int k = 0; k < 8; ++k) {
        int i = grp * 8 + k;
        if (i == j) continue;
        float dx = sx[i] - x, dy = sy[i] - y, dz = sz[i] - z;
        float d = sqrtf(dx * dx + dy * dy + dz * dz + 1e-16f) * A0_INV;
        float ssum = fmaxf(ss2[i] + s2j, 1e-8f);
        float jij = erff(d * rsqrtf(2.0f * ssum)) / d;
        ej = fmaf(sq[i], jij, ej);
    }
    sEsp[grp][j] = ej;
    __syncthreads();
    if (grp == 0) {
        float e = ((sEsp[0][j] + sEsp[1][j]) + (sEsp[2][j] + sEsp[3][j]))
                + ((sEsp[4][j] + sEsp[5][j]) + (sEsp[6][j] + sEsp[7][j]));
        e *= pad;
        float ce = qj * e;
#pragma unroll
        for (int o = 32; o > 0; o >>= 1) ce += __shfl_xor(ce, o);
        if (j == 0) coul[m] = 0.5f * ce;
        qv[atom] = qj;
        esp[atom] = e;
        o_species[atom] = (float)s;
        o_q[atom] = qj;
    }
}

// ---------------- scan (two-level) + work-list build -----------------------
__global__ void bucket_scan_kernel(int* __restrict__ blockCounts,
                                   int* __restrict__ counts, int* __restrict__ offs,
                                   int* __restrict__ workItems, int* __restrict__ workCount,
                                   int nb)
{
    __shared__ int segSum[8][8];
    __shared__ int tot[8];
    const int tid = threadIdx.x;   // 64 threads
    const int seg = tid >> 3, e = tid & 7;
    const int per = (nb + 7) / 8;
    const int b0 = seg * per, b1 = min(b0 + per, nb);
    int run = 0;
    for (int b = b0; b < b1; ++b) run += blockCounts[b * 8 + e];
    segSum[seg][e] = run;
    __syncthreads();
    if (tid < 8) {
        int r = 0;
        for (int s2 = 0; s2 < 8; ++s2) { int c = segSum[s2][tid]; segSum[s2][tid] = r; r += c; }
        tot[tid] = r;
    }
    __syncthreads();
    int runp = segSum[seg][e];
    for (int b = b0; b < b1; ++b) {
        int c = blockCounts[b * 8 + e];
        blockCounts[b * 8 + e] = runp;
        runp += c;
    }
    if (tid == 0) {
        int o = 0;
        for (int i = 0; i < 8; ++i) { offs[i] = o; counts[i] = tot[i]; o += tot[i]; }
        offs[8] = o;
    }
    if (tid < 8) {
        int pos = 0;
        for (int i = 0; i < tid; ++i) pos += (tot[i] + 63) >> 6;
        int nt_e = (tot[tid] + 63) >> 6;
        for (int k = 0; k < nt_e; ++k) workItems[pos + k] = (tid << 20) | (k * 64);
        if (tid == 7) workCount[0] = pos + nt_e;
    }
}

// ---------------- fill: scatter atom ids + zero-init outat -----------------
__global__ __launch_bounds__(256) void bucket_fill_kernel(
    const int* __restrict__ species, const int* __restrict__ blockCounts,
    const int* __restrict__ offs, const int* __restrict__ rank,
    int* __restrict__ bidx, float* __restrict__ outat, int A)
{
    int a = blockIdx.x * 256 + threadIdx.x;
    if (a < A) {
        outat[a] = 0.0f;
        int s = species[a];
        if (s >= 0)
            bidx[offs[s] + blockCounts[(a >> 6) * 8 + s] + rank[a]] = a;
    }
}

// ---- A-fragment loads straight from global (bf16 or fp32 fallback) --------
__device__ __forceinline__ bf16x8 loadA16(const __bf16* __restrict__ aev16,
                                          int atom, int kt, int g)
{
    bf16x8 z = {};
    if (atom < 0) return z;
    return *(const bf16x8*)(aev16 + (long)atom * 384 + kt * 32 + g * 8);
}
__device__ __forceinline__ bf16x8 loadAf(const float* __restrict__ aev,
                                         int atom, int kt, int g)
{
    bf16x8 z = {};
    if (atom < 0) return z;
    const float* p = aev + (long)atom * 384 + kt * 32 + g * 8;
    float4 va = *(const float4*)p, vb = *(const float4*)(p + 4);
    bf16x8 r = {(__bf16)va.x, (__bf16)va.y, (__bf16)va.z, (__bf16)va.w,
                (__bf16)vb.x, (__bf16)vb.y, (__bf16)vb.z, (__bf16)vb.w};
    return r;
}

// ---------------- routed expert MLP: no staging, A-frags from global -------
// launch_bounds (512, 4): VGPR cap 128 (natural use ~88-100) -> NO spills.
// (512,6) in the previous round capped VGPR at 40 -> 28 MB scratch traffic.
template<bool HAVE16>
__global__ __launch_bounds__(512, 4) void expert_mfma_kernel(
    const float* __restrict__ aev, const __bf16* __restrict__ aev16,
    const float* __restrict__ qv, const float* __restrict__ esp,
    const __bf16* __restrict__ bp1, const __bf16* __restrict__ bp2, const __bf16* __restrict__ bp3,
    const float* __restrict__ b1, const float* __restrict__ b2, const float* __restrict__ b3,
    const float* __restrict__ W4, const float* __restrict__ b4,
    const int* __restrict__ counts, const int* __restrict__ offs, const int* __restrict__ bidx,
    const int* __restrict__ workItems, const int* __restrict__ workCount,
    float* __restrict__ outat)
{
    const int bid = blockIdx.x;
    if (bid >= workCount[0]) return;
    const int wi = workItems[bid];
    const int e = wi >> 20;
    const int start = wi & 0xFFFFF;
    const int cnt = counts[e];

    __shared__ __align__(16) unsigned char smem[21504 + 17408];  // 38.9 KB
    __shared__ int said[64];
    __shared__ unsigned int sQE[64];
    __bf16* sAct1 = (__bf16*)smem;              // [64][168]
    __bf16* sAct2 = (__bf16*)(smem + 21504);    // [64][136]
    __bf16* sAct3 = (__bf16*)smem;              // [64][104] (alias dead sAct1)
    const int t = threadIdx.x;

    if (t < 64) {
        int a_ = (start + t < cnt) ? bidx[offs[e] + start + t] : -1;
        said[t] = a_;
        float q = 0.f, es = 0.f;
        if (a_ >= 0) { q = qv[a_]; es = esp[a_]; }
        sQE[t] = ((unsigned)f_to_bf16_bits(es) << 16) | f_to_bf16_bits(q);
    }
    __syncthreads();

    // ---- Layer 1: NT=10, KT=13 (kt 12 = q/esp columns), A from global ----
    {
        const int lane = t & 63, wid = t >> 6;
        const int mw = wid >> 2, nw = wid & 3;
        const int r16 = lane & 15, g = lane >> 4;
        const int atom0 = said[(mw * 2 + 0) * 16 + r16];
        const int atom1 = said[(mw * 2 + 1) * 16 + r16];
        const bf16x8* Bp = (const bf16x8*)bp1 + (size_t)e * 10 * 13 * 64;
        constexpr int NJ = 3;
        f32x4 acc[2][NJ];
#pragma unroll
        for (int mi = 0; mi < 2; ++mi)
#pragma unroll
            for (int j = 0; j < NJ; ++j) acc[mi][j] = (f32x4){0.f, 0.f, 0.f, 0.f};

        bf16x8 bcur[NJ], bnxt[NJ];
#pragma unroll
        for (int j = 0; j < NJ; ++j) {
            const int nt = nw + 4 * j;
            if (nt < 10) bcur[j] = Bp[(nt * 13) * 64 + lane];
        }
        bf16x8 a0c = HAVE16 ? loadA16(aev16, atom0, 0, g) : loadAf(aev, atom0, 0, g);
        bf16x8 a1c = HAVE16 ? loadA16(aev16, atom1, 0, g) : loadAf(aev, atom1, 0, g);

        for (int kt = 0; kt < 12; ++kt) {
#pragma unroll
            for (int j = 0; j < NJ; ++j) {
                const int nt = nw + 4 * j;
                if (nt < 10) bnxt[j] = Bp[(nt * 13 + kt + 1) * 64 + lane];
            }
            bf16x8 a0n, a1n;
            if (kt < 11) {
                a0n = HAVE16 ? loadA16(aev16, atom0, kt + 1, g) : loadAf(aev, atom0, kt + 1, g);
                a1n = HAVE16 ? loadA16(aev16, atom1, kt + 1, g) : loadAf(aev, atom1, kt + 1, g);
            }
#pragma unroll
            for (int j = 0; j < NJ; ++j) {
                const int nt = nw + 4 * j;
                if (nt < 10) {
                    acc[0][j] = __builtin_amdgcn_mfma_f32_16x16x32_bf16(a0c, bcur[j], acc[0][j], 0, 0, 0);
                    acc[1][j] = __builtin_amdgcn_mfma_f32_16x16x32_bf16(a1c, bcur[j], acc[1][j], 0, 0, 0);
                }
            }
#pragma unroll
            for (int j = 0; j < NJ; ++j) bcur[j] = bnxt[j];
            if (kt < 11) { a0c = a0n; a1c = a1n; }
        }
        // kt = 12: only k=384 (q), 385 (esp) nonzero -> g==0, j=0,1
        bf16x8 aq0 = {}, aq1 = {};
        if (g == 0) {
            unsigned qe0 = sQE[(mw * 2 + 0) * 16 + r16];
            unsigned qe1 = sQE[(mw * 2 + 1) * 16 + r16];
            aq0[0] = u16_to_bf16((unsigned short)(qe0 & 0xffff));
            aq0[1] = u16_to_bf16((unsigned short)(qe0 >> 16));
            aq1[0] = u16_to_bf16((unsigned short)(qe1 & 0xffff));
            aq1[1] = u16_to_bf16((unsigned short)(qe1 >> 16));
        }
#pragma unroll
        for (int j = 0; j < NJ; ++j) {
            const int nt = nw + 4 * j;
            if (nt < 10) {
                acc[0][j] = __builtin_amdgcn_mfma_f32_16x16x32_bf16(aq0, bcur[j], acc[0][j], 0, 0, 0);
                acc[1][j] = __builtin_amdgcn_mfma_f32_16x16x32_bf16(aq1, bcur[j], acc[1][j], 0, 0, 0);
            }
        }
        // epilogue -> sAct1
#pragma unroll
        for (int j = 0; j < NJ; ++j) {
            const int nt = nw + 4 * j;
            if (nt < 10) {
                const float bb = b1[e * 160 + nt * 16 + r16];
#pragma unroll
                for (int mi = 0; mi < 2; ++mi)
#pragma unroll
                    for (int r = 0; r < 4; ++r) {
                        float v = acc[mi][j][r] + bb;
                        v = celu01(v);
                        sAct1[((mw * 2 + mi) * 16 + g * 4 + r) * 168 + nt * 16 + r16] = (__bf16)v;
                    }
            }
        }
    }
    __syncthreads();
    mlp_layer8<8, 5, 168, 136, true>(sAct1, (const bf16x8*)bp2 + (size_t)e * 8 * 5 * 64,
                                     b2 + e * 128, sAct2, t);
    __syncthreads();
    mlp_layer8<6, 4, 136, 104, true>(sAct2, (const bf16x8*)bp3 + (size_t)e * 6 * 4 * 64,
                                     b3 + e * 96, sAct3, t);
    __syncthreads();
    if (t < 64) {
        int atom = said[t];
        if (atom >= 0) {
            float acc = l4_dot(sAct3 + t * 104, W4 + e * 96);
            outat[atom] = acc + b4[e];
        }
    }
}

// ---------------- per-molecule energy -----------------------------
__global__ __launch_bounds__(64) void energy_kernel(
    const float* __restrict__ outat, const float* __restrict__ coul,
    float* __restrict__ o_energy)
{
    int m = blockIdx.x, t = threadIdx.x;
    float v = outat[m * 64 + t];
#pragma unroll
    for (int o = 32; o > 0; o >>= 1) v += __shfl_xor(v, o);
    if (t == 0) o_energy[m] = v + coul[m];
}

extern "C" void kernel_launch(void* const* d_in, const int* in_sizes, int n_in,
                              void* d_out, int out_size, void* d_ws, size_t ws_size,
                              hipStream_t stream)
{
    const int*   species = (const int*)  d_in[0];
    const float* coords  = (const float*)d_in[1];
    const float* netq    = (const float*)d_in[2];
    const float* aev     = (const float*)d_in[3];
    const float* cW1 = (const float*)d_in[4];
    const float* cb1 = (const float*)d_in[5];
    const float* cW2 = (const float*)d_in[6];
    const float* cb2 = (const float*)d_in[7];
    const float* cW3 = (const float*)d_in[8];
    const float* cb3 = (const float*)d_in[9];
    const float* cW4 = (const float*)d_in[10];
    const float* cb4 = (const float*)d_in[11];
    const float* W1  = (const float*)d_in[12];
    const float* b1  = (const float*)d_in[13];
    const float* W2  = (const float*)d_in[14];
    const float* b2  = (const float*)d_in[15];
    const float* W3  = (const float*)d_in[16];
    const float* b3  = (const float*)d_in[17];
    const float* W4  = (const float*)d_in[18];
    const float* b4  = (const float*)d_in[19];

    const int N = in_sizes[2];          // 512
    const int n = in_sizes[0] / N;      // 64
    const int A = N * n;                // 32768
    const int nb64 = A / 64;            // 512
    const int maxWork = nb64 + 8;       // 520

    // ---- workspace layout ----
    float* fbase   = (float*)d_ws;
    float* qv      = fbase;
    float* esp     = fbase + (size_t)A;
    float* outat   = fbase + (size_t)2 * A;
    float* coul    = fbase + (size_t)3 * A;
    int*   counts  = (int*)(coul + N);
    int*   offs    = counts + 8;
    int*   workCount = offs + 9;
    int*   workItems = workCount + 1;            // maxWork ints
    int*   blockCounts = workItems + maxWork;    // nb64*8 ints
    int*   rank    = blockCounts + nb64 * 8;     // A ints
    int*   bidx    = rank + A;                   // A ints
    uintptr_t p = ((uintptr_t)(bidx + A) + 15) & ~(uintptr_t)15;
    __bf16* bp_c1 = (__bf16*)p; p += (size_t)10 * 12 * 512 * 2;
    __bf16* bp_c2 = (__bf16*)p; p += (size_t)8  * 5  * 512 * 2;
    __bf16* bp_c3 = (__bf16*)p; p += (size_t)6  * 4  * 512 * 2;
    __bf16* bp_e1 = (__bf16*)p; p += (size_t)8 * 10 * 13 * 512 * 2;
    __bf16* bp_e2 = (__bf16*)p; p += (size_t)8 * 8  * 5  * 512 * 2;
    __bf16* bp_e3 = (__bf16*)p; p += (size_t)8 * 6  * 4  * 512 * 2;
    p = (p + 15) & ~(uintptr_t)15;
    __bf16* aev16 = (__bf16*)p;
    size_t need = (p - (uintptr_t)d_ws) + (size_t)A * 384 * 2;
    if (ws_size < need) aev16 = nullptr;         // fp32 fallback path

    float* o_species = (float*)d_out;        // A elems (species as float)
    float* o_energy  = o_species + A;        // N elems
    float* o_q       = o_energy + N;         // A elems

    pack_all_kernel<<<(111104 + 255) / 256, 256, 0, stream>>>(
        cW1, cW2, cW3, W1, W2, W3, bp_c1, bp_c2, bp_c3, bp_e1, bp_e2, bp_e3);

    chimol_kernel<<<nb64, 512, 0, stream>>>(aev, species, coords, netq,
                                            bp_c1, bp_c2, bp_c3,
                                            cb1, cb2, cb3, cW4, cb4,
                                            aev16, blockCounts, rank,
                                            qv, esp, coul, o_species, o_q);
    bucket_scan_kernel<<<1, 64, 0, stream>>>(blockCounts, counts, offs,
                                             workItems, workCount, nb64);
    bucket_fill_kernel<<<(A + 255) / 256, 256, 0, stream>>>(species, blockCounts, offs,
                                                            rank, bidx, outat, A);
    if (aev16)
        expert_mfma_kernel<true><<<maxWork, 512, 0, stream>>>(
            aev, aev16, qv, esp, bp_e1, bp_e2, bp_e3, b1, b2, b3, W4, b4,
            counts, offs, bidx, workItems, workCount, outat);
    else
        expert_mfma_kernel<false><<<maxWork, 512, 0, stream>>>(
            aev, aev16, qv, esp, bp_e1, bp_e2, bp_e3, b1, b2, b3, W4, b4,
            counts, offs, bidx, workItems, workCount, outat);
    energy_kernel<<<N, 64, 0, stream>>>(outat, coul, o_energy);
}